// Round 13
// baseline (184.273 us; speedup 1.0000x reference)
//
#include <hip/hip_runtime.h>
#include <hip/hip_bf16.h>

#define N_ROWS 8192
#define D_DIM  256

// loss_i = log(sum_{j != i} exp(<x_i,y_j>/T)) - <x_i,y_i>/T ; out = mean_i loss_i
// fp8 e4m3 (scale 64); acc = 4096*<x,y>; 1/4096 folded into constants.
// Both matrices are stored FRAGMENT-MAJOR by cvt: for 64-row band b, MFMA
// lane L = q*16+l15, instr i = mt*4+g (mt=16-row subtile, g=kstep pair):
//   frag16[b][i][L] = M[b*64 + mt*16 + l15][k = (2g+sub)*32 + q*8 + j]
// (16 B per lane: sub=0..1 halves, j=0..7). A wave loads a band's fragments as
// 16 perfectly-coalesced b128 loads straight into registers — no LDS, no
// barriers, no ds_reads anywhere in the hot loop.
static constexpr float kQuantScale = 64.0f;
static constexpr float kScaleAcc = 20.609929155556627f / 4096.0f;  // (1/T)*log2(e)/4096
static constexpr float kInvTAcc  = 14.285714285714286f / 4096.0f;  // (1/T)/4096

typedef float f32x4 __attribute__((ext_vector_type(4)));
typedef long  lx2   __attribute__((ext_vector_type(2)));

// ---------------- fp32 -> fp8 e4m3 pre-convert (fragment-major) + ws init ------
__global__ __launch_bounds__(256)
void cvt_fp8_kernel(const float* __restrict__ x, const float* __restrict__ y,
                    unsigned char* __restrict__ xf, unsigned char* __restrict__ yf,
                    float* __restrict__ rowsum, unsigned int* __restrict__ done) {
  if (blockIdx.x == 0) {
    for (int i = threadIdx.x; i < N_ROWS; i += 256) rowsum[i] = 0.f;
    if (threadIdx.x == 0) *done = 0u;
  }
  const int per_mat = N_ROWS * D_DIM / 8;  // 8 elements per thread
  int idx = blockIdx.x * blockDim.x + threadIdx.x;
  const float* src = x;
  unsigned char* dst = xf;
  int i = idx;
  if (idx >= per_mat) { src = y; dst = yf; i = idx - per_mat; }
  float4 a = ((const float4*)src)[2 * (size_t)i];
  float4 b = ((const float4*)src)[2 * (size_t)i + 1];
  int v0 = 0, v1 = 0;
  v0 = __builtin_amdgcn_cvt_pk_fp8_f32(a.x * kQuantScale, a.y * kQuantScale, v0, false);
  v0 = __builtin_amdgcn_cvt_pk_fp8_f32(a.z * kQuantScale, a.w * kQuantScale, v0, true);
  v1 = __builtin_amdgcn_cvt_pk_fp8_f32(b.x * kQuantScale, b.y * kQuantScale, v1, false);
  v1 = __builtin_amdgcn_cvt_pk_fp8_f32(b.z * kQuantScale, b.w * kQuantScale, v1, true);
  // thread owns row = i>>5, elements k = (i&31)*8 .. +7
  const int row = i >> 5;
  const int c   = i & 31;          // k = c*8+j
  const int q   = c & 3;           // quad
  const int sub = (c >> 2) & 1;    // 8B half within the lane's 16B
  const int g   = c >> 3;          // kstep pair
  const int mt  = (row >> 4) & 3;  // 16-row subtile
  const int l15 = row & 15;
  const int band = row >> 6;
  const size_t off = (size_t)band * 16384 + (mt * 4 + g) * 1024
                   + (q * 16 + l15) * 16 + sub * 8;
  *(int2*)(dst + off) = make_int2(v0, v1);
}

// ---------------- barrier-free fused GEMM(fp8) + exp + row-sum + finalize ------
// 512 blocks (2/CU) x 256 threads (4 waves). Wave = one 64-col Y strip
// (strip = (b&31)*4 + wave), Y fragments resident in 64 VGPRs (loaded once).
// Block's 4 waves share X segment seg = b>>5 (bands seg*8..seg*8+7): each wave
// streams the 8 bands' A-fragments global->VGPR (16 coalesced b128 per band,
// L1-broadcast across the 4 waves). 128 MFMAs + epilogue per band. No LDS, no
// __syncthreads in the loop — waves free-run; MFMA/VALU phases of different
// waves co-schedule (m114). All acc/frag indices compile-time (R10 lesson).
// No per-block fences (R4 lesson); single ticket finalize (R12-validated).
__global__ __launch_bounds__(256, 2)
void infonce_gemm(const unsigned char* __restrict__ Xf,
                  const unsigned char* __restrict__ Yf,
                  float* __restrict__ rowsum, float* __restrict__ diag,
                  unsigned int* __restrict__ done, float* __restrict__ out) {
  __shared__ float red[256];
  __shared__ unsigned int ticket_s;

  const int b    = blockIdx.x;      // 0..511
  const int seg  = b >> 5;          // 0..15: X bands seg*8..+7
  const int sq   = b & 31;          // 0..31: strip quad
  const int t    = threadIdx.x;
  const int lane = t & 63;
  const int wave = t >> 6;          // 0..3
  const int strip = sq * 4 + wave;  // 0..127: this wave's 64-col Y strip
  const int quad = lane >> 4;
  const int l15  = lane & 15;

  // ---- Y strip fragments -> registers (once): 16 coalesced b128 ----
  lx2 yreg[16];
  {
    const lx2* Yb = (const lx2*)(Yf + (size_t)strip * 16384 + lane * 16);
#pragma unroll
    for (int i = 0; i < 16; ++i) yreg[i] = Yb[i * 64];  // instr stride 1024 B
  }

  f32x4 acc[4][4];
#pragma unroll
  for (int a = 0; a < 4; ++a)
#pragma unroll
    for (int c = 0; c < 4; ++c) acc[a][c] = (f32x4){0.f, 0.f, 0.f, 0.f};

  for (int ch = 0; ch < 8; ++ch) {
    const int band = seg * 8 + ch;

    // A-band fragments -> registers: 16 coalesced b128 (L1-shared by 4 waves)
    lx2 areg[16];
    {
      const lx2* Ab = (const lx2*)(Xf + (size_t)band * 16384 + lane * 16);
#pragma unroll
      for (int i = 0; i < 16; ++i) areg[i] = Ab[i * 64];
    }

#pragma unroll
    for (int g = 0; g < 4; ++g)
#pragma unroll
      for (int sub = 0; sub < 2; ++sub)
#pragma unroll
        for (int mt = 0; mt < 4; ++mt)
#pragma unroll
          for (int nt = 0; nt < 4; ++nt)
            acc[mt][nt] = __builtin_amdgcn_mfma_f32_16x16x32_fp8_fp8(
                areg[mt * 4 + g][sub], yreg[nt * 4 + g][sub], acc[mt][nt], 0, 0, 0);

    // ---- tile epilogue: exp + FULL row-sum (diag removed in finalize) ----
    const int gi_base = band * 64;
#pragma unroll
    for (int mt = 0; mt < 4; ++mt) {
#pragma unroll
      for (int rr = 0; rr < 4; ++rr) {
        float part = 0.f;
#pragma unroll
        for (int nt = 0; nt < 4; ++nt)
          part += __builtin_amdgcn_exp2f(acc[mt][nt][rr] * kScaleAcc);
        part += __shfl_xor(part, 1);
        part += __shfl_xor(part, 2);
        part += __shfl_xor(part, 4);
        part += __shfl_xor(part, 8);
        if (l15 == 0) atomicAdd(&rowsum[gi_base + mt * 16 + quad * 4 + rr], part);
      }
    }
    // diagonal tile: this wave owns (strip, band) uniquely; diagonal iff equal.
    if (strip == band) {
#pragma unroll
      for (int nt = 0; nt < 4; ++nt)
#pragma unroll
        for (int rr = 0; rr < 4; ++rr)
          if (l15 == quad * 4 + rr)
            atomicExch(&diag[gi_base + nt * 16 + l15], acc[nt][nt][rr]);
    }
#pragma unroll
    for (int a = 0; a < 4; ++a)
#pragma unroll
      for (int c = 0; c < 4; ++c) acc[a][c] = (f32x4){0.f, 0.f, 0.f, 0.f};
  }

  // ---- last-block finalize (single fence, R12-validated) ----
  __syncthreads();                       // drains this block's atomics (vmcnt)
  if (t == 0) ticket_s = atomicAdd(done, 1u);
  __syncthreads();
  if (ticket_s == 511u) {
    __threadfence();                     // one acquire, one block only
    float local = 0.f;
    for (int i = t; i < N_ROWS; i += 256) {
      const float rs = atomicAdd(&rowsum[i], 0.0f);   // device-coherent read
      const float d  = atomicAdd(&diag[i], 0.0f);
      local += __logf(rs - __builtin_amdgcn_exp2f(d * kScaleAcc)) - d * kInvTAcc;
    }
    red[t] = local;
    __syncthreads();
    for (int s2 = 128; s2 > 0; s2 >>= 1) {
      if (t < s2) red[t] += red[t + s2];
      __syncthreads();
    }
    if (t == 0) out[0] = red[0] / (float)N_ROWS;
  }
}

extern "C" void kernel_launch(void* const* d_in, const int* in_sizes, int n_in,
                              void* d_out, int out_size, void* d_ws, size_t ws_size,
                              hipStream_t stream) {
  const float* x = (const float*)d_in[0];
  const float* y = (const float*)d_in[1];
  float* out = (float*)d_out;

  // ws layout: rowsum[N] f32 | diag[N] f32 | done u32(+pad) | xf | yf
  float* rowsum = (float*)d_ws;
  float* diag   = rowsum + N_ROWS;
  unsigned int* done = (unsigned int*)(diag + N_ROWS);
  unsigned char* xf = (unsigned char*)d_ws + 2 * N_ROWS * sizeof(float) + 16;
  unsigned char* yf = xf + (size_t)N_ROWS * D_DIM;

  int cvt_blocks = 2 * N_ROWS * D_DIM / 8 / 256;  // 2048
  cvt_fp8_kernel<<<cvt_blocks, 256, 0, stream>>>(x, y, xf, yf, rowsum, done);

  infonce_gemm<<<512, 256, 0, stream>>>(xf, yf, rowsum, diag, done, out);
}

// Round 14
// 122.191 us; speedup vs baseline: 1.5081x; 1.5081x over previous
//
#include <hip/hip_runtime.h>
#include <hip/hip_bf16.h>

#define N_ROWS 8192
#define D_DIM  256

// loss_i = log(sum_{j != i} exp(<x_i,y_j>/T)) - <x_i,y_i>/T ; out = mean_i loss_i
// fp8 e4m3 inputs (scale 64); acc = 4096*<x,y>; 1/4096 folded into constants.
// K-dim stored PERMUTED: element k (ks=k>>5, q=(k>>3)&3) stored at
// k' = (ks>>1)*64 + q*16 + (ks&1)*8 + (k&7) -> per lane per 2-kstep group the
// fragment is 16 contiguous bytes (1 ds_read_b128).
static constexpr float kQuantScale = 64.0f;
static constexpr float kScaleAcc = 20.609929155556627f / 4096.0f;  // (1/T)*log2(e)/4096
static constexpr float kInvTAcc  = 14.285714285714286f / 4096.0f;  // (1/T)/4096

typedef float f32x4 __attribute__((ext_vector_type(4)));
typedef long  lx2   __attribute__((ext_vector_type(2)));

// async 16B global->LDS: LDS dest = wave-uniform base + lane*16
__device__ __forceinline__ void gl_lds16(const void* g, void* l) {
  __builtin_amdgcn_global_load_lds(
      (const __attribute__((address_space(1))) void*)g,
      (__attribute__((address_space(3))) void*)l, 16, 0, 0);
}

// ---------------- fp32 -> fp8 e4m3 pre-convert (k-permuted) + ws init ----------
__global__ __launch_bounds__(256)
void cvt_fp8_kernel(const float* __restrict__ x, const float* __restrict__ y,
                    unsigned char* __restrict__ xq, unsigned char* __restrict__ yq,
                    float* __restrict__ rowsum, unsigned int* __restrict__ done) {
  if (blockIdx.x == 0) {
    for (int i = threadIdx.x; i < N_ROWS; i += 256) rowsum[i] = 0.f;
    if (threadIdx.x == 0) *done = 0u;
  }
  const int per_mat = N_ROWS * D_DIM / 8;  // 8 elements per thread
  int idx = blockIdx.x * blockDim.x + threadIdx.x;
  const float* src = x;
  unsigned char* dst = xq;
  int i = idx;
  if (idx >= per_mat) { src = y; dst = yq; i = idx - per_mat; }
  float4 a = ((const float4*)src)[2 * (size_t)i];
  float4 b = ((const float4*)src)[2 * (size_t)i + 1];
  int v0 = 0, v1 = 0;
  v0 = __builtin_amdgcn_cvt_pk_fp8_f32(a.x * kQuantScale, a.y * kQuantScale, v0, false);
  v0 = __builtin_amdgcn_cvt_pk_fp8_f32(a.z * kQuantScale, a.w * kQuantScale, v0, true);
  v1 = __builtin_amdgcn_cvt_pk_fp8_f32(b.x * kQuantScale, b.y * kQuantScale, v1, false);
  v1 = __builtin_amdgcn_cvt_pk_fp8_f32(b.z * kQuantScale, b.w * kQuantScale, v1, true);
  // elements k = c*8..c*8+7, c = ks*4 + q; store at (ks>>1)*64 + q*16 + (ks&1)*8
  const int row = i >> 5;
  const int c   = i & 31;
  const int ks  = c >> 2;
  const int q   = c & 3;
  const size_t off = (size_t)row * D_DIM + (ks >> 1) * 64 + q * 16 + (ks & 1) * 8;
  *(int2*)(dst + off) = make_int2(v0, v1);
}

// ---------------- persistent fused GEMM(fp8) + exp + row-sum + finalize --------
// R12 chassis: 256 persistent blocks (1/CU), 512 threads = 8 waves (wm 0..3,
// wn 0..1). X-block (256 rows, full K) staged once (64 KB); Y: 8 tiles of
// 128 cols full-K double-buffered (64 KB). 8 rounds, one barrier per tile.
// KEY CHANGE (R14): row-sum accumulates in LDS (ds_add_f32, lgkmcnt domain) —
// NO global atomics inside the round loop, so the vmcnt FIFO between barriers
// holds only staging loads (atomic-retire latency was the cross-structure
// plateau suspect). One global atomicAdd per row per block after the loop.
// All acc indices compile-time (R10). No per-block fences (R4). Single-fence
// ticket finalize (R12-validated).
__global__ __launch_bounds__(512, 1)
void infonce_gemm(const unsigned char* __restrict__ X,
                  const unsigned char* __restrict__ Y,
                  float* __restrict__ rowsum, float* __restrict__ diag,
                  unsigned int* __restrict__ done, float* __restrict__ out) {
  __shared__ unsigned char Xs[256 * 256];      // 64 KB, X-block full-K
  __shared__ unsigned char Ys[2][128 * 256];   // 2 x 32 KB, Y tile dbuf
  __shared__ float lds_rs[256];                // per-block row sums (local rows)
  __shared__ unsigned int ticket_s;

  const int b  = blockIdx.x;        // 0..255
  const int bi = b >> 3;            // 0..31: X-row-block (256 rows)
  const int gj = b & 7;             // col-group: col-tile ct = gj*8 + tt

  const int t    = threadIdx.x;
  const int lane = t & 63;
  const int wave = t >> 6;        // 0..7
  const int wm   = wave >> 1;     // 0..3  (64-row band)
  const int wn   = wave & 1;      // 0..1  (64-col half)
  const int quad = lane >> 4;     // 0..3
  const int l15  = lane & 15;

  const unsigned char* Xblk = X + (size_t)(bi * 256) * D_DIM;

  if (t < 256) lds_rs[t] = 0.f;    // visible after the first __syncthreads

  // ---- prologue: stage X (4096 slots of 16B, 8 per thread) ----
#pragma unroll
  for (int it = 0; it < 8; ++it) {
    const int c0  = (it * 8 + wave) * 64;
    const int s   = c0 + lane;
    const int row = s >> 4;                 // 0..255
    const int cg  = (s & 15) ^ (row & 15);  // inverse swizzle on global side
    gl_lds16(Xblk + (size_t)row * D_DIM + cg * 16, &Xs[c0 * 16]);
  }
  // stage Y tile 0 (2048 slots, 4 per thread) into buffer 0
  {
    const unsigned char* Yblk = Y + (size_t)(gj * 8) * 128 * D_DIM;
#pragma unroll
    for (int it = 0; it < 4; ++it) {
      const int c0  = (it * 8 + wave) * 64;
      const int s   = c0 + lane;
      const int row = s >> 4;                 // 0..127
      const int cg  = (s & 15) ^ (row & 15);
      gl_lds16(Yblk + (size_t)row * D_DIM + cg * 16, &Ys[0][c0 * 16]);
    }
  }

  f32x4 acc[4][4];
#pragma unroll
  for (int a = 0; a < 4; ++a)
#pragma unroll
    for (int c = 0; c < 4; ++c) acc[a][c] = (f32x4){0.f, 0.f, 0.f, 0.f};

  for (int tt = 0; tt < 8; ++tt) {
    const int p = tt & 1;

    __syncthreads();   // round tt staged (vmcnt holds ONLY staging loads now)

    if (tt < 7) {      // stage Y tile tt+1 into the other buffer
      const unsigned char* Yblk = Y + (size_t)(gj * 8 + tt + 1) * 128 * D_DIM;
#pragma unroll
      for (int it = 0; it < 4; ++it) {
        const int c0  = (it * 8 + wave) * 64;
        const int s   = c0 + lane;
        const int row = s >> 4;
        const int cg  = (s & 15) ^ (row & 15);
        gl_lds16(Yblk + (size_t)row * D_DIM + cg * 16, &Ys[p ^ 1][c0 * 16]);
      }
    }

    // full-K compute: 4 groups of 2 k-steps; 1 b128 per fragment per group
#pragma unroll
    for (int g = 0; g < 4; ++g) {
      lx2 af[4], bfr[4];
#pragma unroll
      for (int mt = 0; mt < 4; ++mt) {
        const int row = wm * 64 + mt * 16 + l15;
        const int pos = (g * 4 + quad) ^ l15;       // row&15 == l15
        af[mt] = *(const lx2*)(&Xs[row * 256 + pos * 16]);
      }
#pragma unroll
      for (int nt = 0; nt < 4; ++nt) {
        const int row = wn * 64 + nt * 16 + l15;
        const int pos = (g * 4 + quad) ^ l15;
        bfr[nt] = *(const lx2*)(&Ys[p][row * 256 + pos * 16]);
      }
#pragma unroll
      for (int sub = 0; sub < 2; ++sub)
#pragma unroll
        for (int mt = 0; mt < 4; ++mt)
#pragma unroll
          for (int nt = 0; nt < 4; ++nt)
            acc[mt][nt] = __builtin_amdgcn_mfma_f32_16x16x32_fp8_fp8(
                af[mt][sub], bfr[nt][sub], acc[mt][nt], 0, 0, 0);
    }

    // ---- tile epilogue: exp + row-sum into LDS (ds_add_f32, lgkm domain) ----
#pragma unroll
    for (int mt = 0; mt < 4; ++mt) {
#pragma unroll
      for (int rr = 0; rr < 4; ++rr) {
        float part = 0.f;
#pragma unroll
        for (int nt = 0; nt < 4; ++nt)
          part += __builtin_amdgcn_exp2f(acc[mt][nt][rr] * kScaleAcc);
        part += __shfl_xor(part, 1);
        part += __shfl_xor(part, 2);
        part += __shfl_xor(part, 4);
        part += __shfl_xor(part, 8);
        if (l15 == 0)
          atomicAdd(&lds_rs[wm * 64 + mt * 16 + quad * 4 + rr], part);
      }
    }
    // diagonal: col-tile ct overlaps rows iff ct==2*bi (wm==wn) or 2*bi+1
    // (wm==wn+2). Device-scope atomicExch so the last block reads coherently.
    {
      const int ct = gj * 8 + tt;
      const bool d0 = (ct == 2 * bi)     && (wm == wn);
      const bool d1 = (ct == 2 * bi + 1) && (wm == wn + 2);
      if (d0 || d1) {
        const int gi_base = bi * 256 + wm * 64;
#pragma unroll
        for (int nt = 0; nt < 4; ++nt)
#pragma unroll
          for (int rr = 0; rr < 4; ++rr)
            if (l15 == quad * 4 + rr)
              atomicExch(&diag[gi_base + nt * 16 + l15], acc[nt][nt][rr]);
      }
    }
#pragma unroll
    for (int a = 0; a < 4; ++a)
#pragma unroll
      for (int c = 0; c < 4; ++c) acc[a][c] = (f32x4){0.f, 0.f, 0.f, 0.f};
  }

  // ---- flush LDS row sums to global (one atomic per row, off critical path) ----
  __syncthreads();                       // lds_rs complete
  if (t < 256) atomicAdd(&rowsum[bi * 256 + t], lds_rs[t]);

  // ---- last-block finalize (single fence — R12-validated) ----
  __syncthreads();                       // drains this block's atomics (vmcnt)
  if (t == 0) ticket_s = atomicAdd(done, 1u);
  __syncthreads();
  if (ticket_s == 255u) {
    __threadfence();                     // one acquire, one block only
    float local = 0.f;
    for (int i = t; i < N_ROWS; i += 512) {
      const float rs = atomicAdd(&rowsum[i], 0.0f);   // device-coherent read
      const float d  = atomicAdd(&diag[i], 0.0f);
      local += __logf(rs - __builtin_amdgcn_exp2f(d * kScaleAcc)) - d * kInvTAcc;
    }
    float* red = (float*)Xs;
    red[t] = local;
    __syncthreads();
    for (int s2 = 256; s2 > 0; s2 >>= 1) {
      if (t < s2) red[t] += red[t + s2];
      __syncthreads();
    }
    if (t == 0) out[0] = red[0] / (float)N_ROWS;
  }
}

extern "C" void kernel_launch(void* const* d_in, const int* in_sizes, int n_in,
                              void* d_out, int out_size, void* d_ws, size_t ws_size,
                              hipStream_t stream) {
  const float* x = (const float*)d_in[0];
  const float* y = (const float*)d_in[1];
  float* out = (float*)d_out;

  // ws layout: rowsum[N] f32 | diag[N] f32 | done u32(+pad) | xq | yq
  float* rowsum = (float*)d_ws;
  float* diag   = rowsum + N_ROWS;
  unsigned int* done = (unsigned int*)(diag + N_ROWS);
  unsigned char* xq = (unsigned char*)d_ws + 2 * N_ROWS * sizeof(float) + 16;
  unsigned char* yq = xq + (size_t)N_ROWS * D_DIM;

  int cvt_blocks = 2 * N_ROWS * D_DIM / 8 / 256;  // 2048
  cvt_fp8_kernel<<<cvt_blocks, 256, 0, stream>>>(x, y, xq, yq, rowsum, done);

  infonce_gemm<<<256, 512, 0, stream>>>(xq, yq, rowsum, diag, done, out);
}

// Round 15
// 113.597 us; speedup vs baseline: 1.6222x; 1.0756x over previous
//
#include <hip/hip_runtime.h>
#include <hip/hip_bf16.h>

#define N_ROWS 8192
#define D_DIM  256

// loss_i = log(sum_{j != i} exp(<x_i,y_j>/T)) - <x_i,y_i>/T ; out = mean_i loss_i
// fp8 e4m3 inputs (scale 64), PLAIN row-major layout; acc = 4096*<x,y> via
// MX-scaled MFMA 16x16x128 (unit E8M0 scales = exact fp8 dot); 1/4096 folded
// into the constants.
static constexpr float kQuantScale = 64.0f;
static constexpr float kScaleAcc = 20.609929155556627f / 4096.0f;  // (1/T)*log2(e)/4096
static constexpr float kInvTAcc  = 14.285714285714286f / 4096.0f;  // (1/T)/4096

typedef float f32x4 __attribute__((ext_vector_type(4)));
typedef int   i32x4 __attribute__((ext_vector_type(4)));
typedef int   i32x8 __attribute__((ext_vector_type(8)));

// async 16B global->LDS: LDS dest = wave-uniform base + lane*16
__device__ __forceinline__ void gl_lds16(const void* g, void* l) {
  __builtin_amdgcn_global_load_lds(
      (const __attribute__((address_space(1))) void*)g,
      (__attribute__((address_space(3))) void*)l, 16, 0, 0);
}

// ---------------- fp32 -> fp8 e4m3 pre-convert (plain layout) + ws init --------
__global__ __launch_bounds__(256)
void cvt_fp8_kernel(const float* __restrict__ x, const float* __restrict__ y,
                    unsigned char* __restrict__ xq, unsigned char* __restrict__ yq,
                    float* __restrict__ rowsum, unsigned int* __restrict__ done) {
  if (blockIdx.x == 0) {
    for (int i = threadIdx.x; i < N_ROWS; i += 256) rowsum[i] = 0.f;
    if (threadIdx.x == 0) *done = 0u;
  }
  const int per_mat = N_ROWS * D_DIM / 8;  // 8 elements per thread
  int idx = blockIdx.x * blockDim.x + threadIdx.x;
  const float* src = x;
  unsigned char* dst = xq;
  int i = idx;
  if (idx >= per_mat) { src = y; dst = yq; i = idx - per_mat; }
  float4 a = ((const float4*)src)[2 * (size_t)i];
  float4 b = ((const float4*)src)[2 * (size_t)i + 1];
  int v0 = 0, v1 = 0;
  v0 = __builtin_amdgcn_cvt_pk_fp8_f32(a.x * kQuantScale, a.y * kQuantScale, v0, false);
  v0 = __builtin_amdgcn_cvt_pk_fp8_f32(a.z * kQuantScale, a.w * kQuantScale, v0, true);
  v1 = __builtin_amdgcn_cvt_pk_fp8_f32(b.x * kQuantScale, b.y * kQuantScale, v1, false);
  v1 = __builtin_amdgcn_cvt_pk_fp8_f32(b.z * kQuantScale, b.w * kQuantScale, v1, true);
  *(int2*)(dst + (size_t)i * 8) = make_int2(v0, v1);   // plain row-major
}

// ---------------- persistent fused GEMM(MX-fp8) + exp + row-sum + finalize -----
// R14 chassis unchanged: 256 persistent blocks (1/CU), 512 threads = 8 waves
// (wm 0..3, wn 0..1). X-block (256 rows, full K) staged once (64 KB); Y: 8
// tiles of 128 cols full-K double-buffered (64 KB). 8 rounds, one barrier per
// tile. Row-sums in LDS (R14); diag via device-scope atomicExch; single-fence
// ticket finalize (R12). All acc indices compile-time (R10). No per-block
// fences (R4).
// R15 CHANGE: mfma_scale_f32_16x16x128_f8f6f4 with unit scales — 32 MFMA/wave
// per round instead of 128 (4x fewer instrs, ~2.3x less matrix-pipe time).
// Lane (q=quad, l15) A-operand = rows l15, k = q*32..q*32+31 (32 contiguous
// bytes = 2 b128 from swizzled LDS; swizzle pos = chunk ^ (row&15), 2-way max).
__global__ __launch_bounds__(512, 1)
void infonce_gemm(const unsigned char* __restrict__ X,
                  const unsigned char* __restrict__ Y,
                  float* __restrict__ rowsum, float* __restrict__ diag,
                  unsigned int* __restrict__ done, float* __restrict__ out) {
  __shared__ unsigned char Xs[256 * 256];      // 64 KB, X-block full-K
  __shared__ unsigned char Ys[2][128 * 256];   // 2 x 32 KB, Y tile dbuf
  __shared__ float lds_rs[256];                // per-block row sums (local rows)
  __shared__ unsigned int ticket_s;

  const int b  = blockIdx.x;        // 0..255
  const int bi = b >> 3;            // 0..31: X-row-block (256 rows)
  const int gj = b & 7;             // col-group: col-tile ct = gj*8 + tt

  const int t    = threadIdx.x;
  const int lane = t & 63;
  const int wave = t >> 6;        // 0..7
  const int wm   = wave >> 1;     // 0..3  (64-row band)
  const int wn   = wave & 1;      // 0..1  (64-col half)
  const int quad = lane >> 4;     // 0..3
  const int l15  = lane & 15;

  const unsigned char* Xblk = X + (size_t)(bi * 256) * D_DIM;

  if (t < 256) lds_rs[t] = 0.f;    // visible after the first __syncthreads

  // ---- prologue: stage X (4096 slots of 16B, 8 per thread) ----
#pragma unroll
  for (int it = 0; it < 8; ++it) {
    const int c0  = (it * 8 + wave) * 64;
    const int s   = c0 + lane;
    const int row = s >> 4;                 // 0..255
    const int cg  = (s & 15) ^ (row & 15);  // inverse swizzle on global side
    gl_lds16(Xblk + (size_t)row * D_DIM + cg * 16, &Xs[c0 * 16]);
  }
  // stage Y tile 0 (2048 slots, 4 per thread) into buffer 0
  {
    const unsigned char* Yblk = Y + (size_t)(gj * 8) * 128 * D_DIM;
#pragma unroll
    for (int it = 0; it < 4; ++it) {
      const int c0  = (it * 8 + wave) * 64;
      const int s   = c0 + lane;
      const int row = s >> 4;                 // 0..127
      const int cg  = (s & 15) ^ (row & 15);
      gl_lds16(Yblk + (size_t)row * D_DIM + cg * 16, &Ys[0][c0 * 16]);
    }
  }

  f32x4 acc[4][4];
#pragma unroll
  for (int a = 0; a < 4; ++a)
#pragma unroll
    for (int c = 0; c < 4; ++c) acc[a][c] = (f32x4){0.f, 0.f, 0.f, 0.f};

  for (int tt = 0; tt < 8; ++tt) {
    const int p = tt & 1;

    __syncthreads();   // round tt staged (vmcnt holds only staging loads)

    if (tt < 7) {      // stage Y tile tt+1 into the other buffer
      const unsigned char* Yblk = Y + (size_t)(gj * 8 + tt + 1) * 128 * D_DIM;
#pragma unroll
      for (int it = 0; it < 4; ++it) {
        const int c0  = (it * 8 + wave) * 64;
        const int s   = c0 + lane;
        const int row = s >> 4;
        const int cg  = (s & 15) ^ (row & 15);
        gl_lds16(Yblk + (size_t)row * D_DIM + cg * 16, &Ys[p ^ 1][c0 * 16]);
      }
    }

    // full-K compute: 2 MX k-blocks of 128; per (kb): 8 frag b128-pairs + 16 MFMA
#pragma unroll
    for (int kb = 0; kb < 2; ++kb) {
      i32x8 a8[4], b8[4];
#pragma unroll
      for (int mt = 0; mt < 4; ++mt) {
        const int row = wm * 64 + mt * 16 + l15;
        const int p0  = (kb * 8 + quad * 2 + 0) ^ (row & 15);
        const int p1  = (kb * 8 + quad * 2 + 1) ^ (row & 15);
        i32x4 lo = *(const i32x4*)(&Xs[row * 256 + p0 * 16]);
        i32x4 hi = *(const i32x4*)(&Xs[row * 256 + p1 * 16]);
        a8[mt] = __builtin_shufflevector(lo, hi, 0, 1, 2, 3, 4, 5, 6, 7);
      }
#pragma unroll
      for (int nt = 0; nt < 4; ++nt) {
        const int row = wn * 64 + nt * 16 + l15;
        const int p0  = (kb * 8 + quad * 2 + 0) ^ (row & 15);
        const int p1  = (kb * 8 + quad * 2 + 1) ^ (row & 15);
        i32x4 lo = *(const i32x4*)(&Ys[p][row * 256 + p0 * 16]);
        i32x4 hi = *(const i32x4*)(&Ys[p][row * 256 + p1 * 16]);
        b8[nt] = __builtin_shufflevector(lo, hi, 0, 1, 2, 3, 4, 5, 6, 7);
      }
#pragma unroll
      for (int mt = 0; mt < 4; ++mt)
#pragma unroll
        for (int nt = 0; nt < 4; ++nt)
          acc[mt][nt] = __builtin_amdgcn_mfma_scale_f32_16x16x128_f8f6f4(
              a8[mt], b8[nt], acc[mt][nt],
              0, 0,                    // cbsz=fp8 e4m3, blgp=fp8 e4m3
              0, 0x7F7F7F7F,           // A scales = 1.0 (E8M0 127)
              0, 0x7F7F7F7F);          // B scales = 1.0
    }

    // ---- tile epilogue: exp + row-sum into LDS (lgkm domain, R14) ----
#pragma unroll
    for (int mt = 0; mt < 4; ++mt) {
#pragma unroll
      for (int rr = 0; rr < 4; ++rr) {
        float part = 0.f;
#pragma unroll
        for (int nt = 0; nt < 4; ++nt)
          part += __builtin_amdgcn_exp2f(acc[mt][nt][rr] * kScaleAcc);
        part += __shfl_xor(part, 1);
        part += __shfl_xor(part, 2);
        part += __shfl_xor(part, 4);
        part += __shfl_xor(part, 8);
        if (l15 == 0)
          atomicAdd(&lds_rs[wm * 64 + mt * 16 + quad * 4 + rr], part);
      }
    }
    // diagonal: col-tile ct overlaps rows iff ct==2*bi (wm==wn) or 2*bi+1
    // (wm==wn+2). Device-scope atomicExch so the last block reads coherently.
    {
      const int ct = gj * 8 + tt;
      const bool d0 = (ct == 2 * bi)     && (wm == wn);
      const bool d1 = (ct == 2 * bi + 1) && (wm == wn + 2);
      if (d0 || d1) {
        const int gi_base = bi * 256 + wm * 64;
#pragma unroll
        for (int nt = 0; nt < 4; ++nt)
#pragma unroll
          for (int rr = 0; rr < 4; ++rr)
            if (l15 == quad * 4 + rr)
              atomicExch(&diag[gi_base + nt * 16 + l15], acc[nt][nt][rr]);
      }
    }
#pragma unroll
    for (int a = 0; a < 4; ++a)
#pragma unroll
      for (int c = 0; c < 4; ++c) acc[a][c] = (f32x4){0.f, 0.f, 0.f, 0.f};
  }

  // ---- flush LDS row sums to global (one atomic per row, off critical path) ----
  __syncthreads();                       // lds_rs complete
  if (t < 256) atomicAdd(&rowsum[bi * 256 + t], lds_rs[t]);

  // ---- last-block finalize (single fence — R12-validated) ----
  __syncthreads();                       // drains this block's atomics (vmcnt)
  if (t == 0) ticket_s = atomicAdd(done, 1u);
  __syncthreads();
  if (ticket_s == 255u) {
    __threadfence();                     // one acquire, one block only
    float local = 0.f;
    for (int i = t; i < N_ROWS; i += 512) {
      const float rs = atomicAdd(&rowsum[i], 0.0f);   // device-coherent read
      const float d  = atomicAdd(&diag[i], 0.0f);
      local += __logf(rs - __builtin_amdgcn_exp2f(d * kScaleAcc)) - d * kInvTAcc;
    }
    float* red = (float*)Xs;
    red[t] = local;
    __syncthreads();
    for (int s2 = 256; s2 > 0; s2 >>= 1) {
      if (t < s2) red[t] += red[t + s2];
      __syncthreads();
    }
    if (t == 0) out[0] = red[0] / (float)N_ROWS;
  }
}

extern "C" void kernel_launch(void* const* d_in, const int* in_sizes, int n_in,
                              void* d_out, int out_size, void* d_ws, size_t ws_size,
                              hipStream_t stream) {
  const float* x = (const float*)d_in[0];
  const float* y = (const float*)d_in[1];
  float* out = (float*)d_out;

  // ws layout: rowsum[N] f32 | diag[N] f32 | done u32(+pad) | xq | yq
  float* rowsum = (float*)d_ws;
  float* diag   = rowsum + N_ROWS;
  unsigned int* done = (unsigned int*)(diag + N_ROWS);
  unsigned char* xq = (unsigned char*)d_ws + 2 * N_ROWS * sizeof(float) + 16;
  unsigned char* yq = xq + (size_t)N_ROWS * D_DIM;

  int cvt_blocks = 2 * N_ROWS * D_DIM / 8 / 256;  // 2048
  cvt_fp8_kernel<<<cvt_blocks, 256, 0, stream>>>(x, y, xq, yq, rowsum, done);

  infonce_gemm<<<256, 512, 0, stream>>>(xq, yq, rowsum, diag, done, out);
}